// Round 2
// baseline (3433.390 us; speedup 1.0000x reference)
//
#include <hip/hip_runtime.h>

// ---- problem constants -------------------------------------------------
#define NB    128                 // batch
#define NCIN  64                  // conv1 in channels
#define NT    2048                // time
#define HD    128                 // hidden / heads*feat
#define NK    9                   // kernel size
#define NE    600000              // edges
#define NNODE (NB*NT)             // 262144 nodes
#define NTOT  (NE + NNODE)        // edges + self loops = 862144
static const size_t NELEM = (size_t)NNODE * HD;   // 33554432

typedef unsigned int u32;

// ordered-uint mapping for float atomic max
__device__ __forceinline__ u32 fkey(float f) {
  u32 b = __float_as_uint(f);
  return (b & 0x80000000u) ? ~b : (b | 0x80000000u);
}
__device__ __forceinline__ float funkey(u32 u) {
  u32 b = (u & 0x80000000u) ? (u & 0x7fffffffu) : ~u;
  return __uint_as_float(b);
}

// ---- edge index layout detection (int64 vs int32) ----------------------
__global__ __launch_bounds__(256) void detect_edges(const int* __restrict__ ebuf,
                                                    int* __restrict__ flag) {
  __shared__ int s;
  if (threadIdx.x == 0) s = 0;
  __syncthreads();
  int any = 0;
  for (int i = threadIdx.x; i < 512; i += 256)
    if (ebuf[2 * i + 1] != 0) any = 1;           // int64 LE -> high words are 0
  if (any) atomicOr(&s, 1);
  __syncthreads();
  if (threadIdx.x == 0) *flag = s;               // s!=0 -> buffer is int32
}

__global__ __launch_bounds__(256) void convert_edges(const int* __restrict__ ebuf,
                                                     const int* __restrict__ flag,
                                                     int* __restrict__ out) {
  int i = blockIdx.x * 256 + threadIdx.x;
  if (i >= 2 * NE) return;
  out[i] = (*flag) ? ebuf[i] : ebuf[2 * i];      // int64: take low word
}

// ---- conv1d SAME K=9, optional fused BN-affine on input (scale/shift by t%128)
template<int CI, bool AFFINE>
__global__ __launch_bounds__(256) void conv_kernel(
    const float* __restrict__ xin, const float* __restrict__ w,
    const float* __restrict__ bias, const float* __restrict__ scale,
    const float* __restrict__ shift, float* __restrict__ out)
{
  const int t0 = blockIdx.x * 128;
  const int o0 = blockIdx.y * 32;
  const int b  = blockIdx.z;
  __shared__ __align__(16) float xs[16][140];    // 16 ch x (128+8) t, padded row
  __shared__ float wsm[32][16][10];              // 32 o x 16 ci x 9 k (pad)
  const int tid = threadIdx.x;
  const int tg  = tid & 31;                      // 32 t-groups * 4 t
  const int og  = tid >> 5;                      // 8 o-groups * 4 o
  float acc[4][4] = {};
  const float* xb = xin + (size_t)b * CI * NT;
  for (int cc = 0; cc < CI; cc += 16) {
    for (int i = tid; i < 16 * 136; i += 256) {
      const int ci = i / 136, j = i - ci * 136;
      const int gt = t0 + j - 4;
      float v = 0.f;
      if (gt >= 0 && gt < NT) {
        v = xb[(size_t)(cc + ci) * NT + gt];
        if (AFFINE) v = v * scale[gt & 127] + shift[gt & 127];
      }
      xs[ci][j] = v;
    }
    for (int i = tid; i < 32 * 16 * 9; i += 256) {
      const int oo = i / 144, r = i - oo * 144;
      const int ci = r / 9, k = r - ci * 9;
      wsm[oo][ci][k] = w[((size_t)(o0 + oo) * CI + (cc + ci)) * NK + k];
    }
    __syncthreads();
    for (int ci = 0; ci < 16; ++ci) {
      const float4* xr4 = reinterpret_cast<const float4*>(&xs[ci][0]);
      const float4 a0 = xr4[tg], a1 = xr4[tg + 1], a2 = xr4[tg + 2];
      const float xw[12] = {a0.x,a0.y,a0.z,a0.w, a1.x,a1.y,a1.z,a1.w,
                            a2.x,a2.y,a2.z,a2.w};
      #pragma unroll
      for (int oo = 0; oo < 4; ++oo) {
        #pragma unroll
        for (int k = 0; k < NK; ++k) {
          const float wv = wsm[og * 4 + oo][ci][k];
          #pragma unroll
          for (int tt = 0; tt < 4; ++tt) acc[oo][tt] += wv * xw[tt + k];
        }
      }
    }
    __syncthreads();
  }
  #pragma unroll
  for (int oo = 0; oo < 4; ++oo) {
    const int o = o0 + og * 4 + oo;
    const float bv = bias[o];
    float4 v4;
    float* vp = &v4.x;
    #pragma unroll
    for (int tt = 0; tt < 4; ++tt) {
      const float v = acc[oo][tt] + bv;
      vp[tt] = v > 0.f ? v : 0.f;
    }
    *reinterpret_cast<float4*>(&out[((size_t)b * HD + o) * NT + t0 + tg * 4]) = v4;
  }
}

// ---- fused xl = nf@Wl.T+bl, xr = nf@Wr.T+br ----------------------------
__global__ __launch_bounds__(256) void gemm_xlxr(
    const float* __restrict__ nf, const float* __restrict__ Wl,
    const float* __restrict__ bl, const float* __restrict__ Wr,
    const float* __restrict__ br, float* __restrict__ xl, float* __restrict__ xr)
{
  const int n0 = blockIdx.x * 64;
  __shared__ float nfs[64][17];
  __shared__ float wls[128][17];
  __shared__ float wrs[128][17];
  const int tid = threadIdx.x;
  const int tn = tid & 15;                       // 16 groups * 4 rows
  const int tj = tid >> 4;                       // 16 groups * 8 cols
  float accl[4][8] = {}, accr[4][8] = {};
  for (int f0 = 0; f0 < HD; f0 += 16) {
    for (int i = tid; i < 64 * 16; i += 256) {
      const int r = i >> 4, c = i & 15;
      nfs[r][c] = nf[(size_t)(n0 + r) * HD + f0 + c];
    }
    for (int i = tid; i < 128 * 16; i += 256) {
      const int r = i >> 4, c = i & 15;
      wls[r][c] = Wl[r * HD + f0 + c];
      wrs[r][c] = Wr[r * HD + f0 + c];
    }
    __syncthreads();
    #pragma unroll
    for (int k = 0; k < 16; ++k) {
      float a[4], wl8[8], wr8[8];
      #pragma unroll
      for (int i = 0; i < 4; ++i) a[i] = nfs[tn * 4 + i][k];
      #pragma unroll
      for (int j = 0; j < 8; ++j) { wl8[j] = wls[tj * 8 + j][k]; wr8[j] = wrs[tj * 8 + j][k]; }
      #pragma unroll
      for (int i = 0; i < 4; ++i)
        #pragma unroll
        for (int j = 0; j < 8; ++j) { accl[i][j] += a[i] * wl8[j]; accr[i][j] += a[i] * wr8[j]; }
    }
    __syncthreads();
  }
  #pragma unroll
  for (int i = 0; i < 4; ++i) {
    const size_t row = (size_t)(n0 + tn * 4 + i) * HD;
    #pragma unroll
    for (int j = 0; j < 8; ++j) {
      const int col = tj * 8 + j;
      xl[row + col] = accl[i][j] + bl[col];
      xr[row + col] = accr[i][j] + br[col];
    }
  }
}

// ---- per-edge attention score + segment max ----------------------------
__global__ __launch_bounds__(256) void edge_score(
    const int* __restrict__ esrc, const int* __restrict__ edst,
    const float* __restrict__ xl, const float* __restrict__ xr,
    const float* __restrict__ att, float* __restrict__ ebuf, u32* __restrict__ mkey)
{
  const int eid = blockIdx.x * 4 + (threadIdx.x >> 6);
  const int lane = threadIdx.x & 63;
  if (eid >= NTOT) return;
  int s_, d_;
  if (eid < NE) { s_ = esrc[eid]; d_ = edst[eid]; } else { s_ = d_ = eid - NE; }
  const float* xls = xl + (size_t)s_ * HD;
  const float* xrd = xr + (size_t)d_ * HD;
  float v = 0.f;
  #pragma unroll
  for (int f = lane; f < HD; f += 64) {
    float q = xls[f] + xrd[f];
    q = q > 0.f ? q : 0.2f * q;
    v += att[f] * q;
  }
  #pragma unroll
  for (int off = 32; off > 0; off >>= 1) v += __shfl_xor(v, off);
  if (lane == 0) { ebuf[eid] = v; atomicMax(mkey + d_, fkey(v)); }
}

// ---- exp/softmax-denominator + weighted message aggregation ------------
__global__ __launch_bounds__(256) void edge_aggregate(
    const int* __restrict__ esrc, const int* __restrict__ edst,
    const float* __restrict__ xl, const float* __restrict__ ebuf,
    const u32* __restrict__ mkey, float* __restrict__ agg, float* __restrict__ denom)
{
  const int eid = blockIdx.x * 4 + (threadIdx.x >> 6);
  const int lane = threadIdx.x & 63;
  if (eid >= NTOT) return;
  int s_, d_;
  if (eid < NE) { s_ = esrc[eid]; d_ = edst[eid]; } else { s_ = d_ = eid - NE; }
  const float a = expf(ebuf[eid] - funkey(mkey[d_]));
  if (lane == 0) atomicAdd(denom + d_, a);
  const float* xls = xl + (size_t)s_ * HD;
  float* ag = agg + (size_t)d_ * HD;
  atomicAdd(ag + lane,      a * xls[lane]);
  atomicAdd(ag + lane + 64, a * xls[lane + 64]);
}

// ---- finalize GAT (div, bias, relu) + BN statistics --------------------
__global__ __launch_bounds__(256) void gat_finalize(
    const float* __restrict__ agg, const float* __restrict__ denom,
    const float* __restrict__ gbias, float* __restrict__ out0, float* __restrict__ stats)
{
  const int n0 = blockIdx.x * 64;
  const int f  = threadIdx.x & 127;
  const int rh = threadIdx.x >> 7;
  const float bv = gbias[f];
  float s1 = 0.f, s2 = 0.f;
  for (int r = rh; r < 64; r += 2) {
    const size_t idx = (size_t)(n0 + r) * HD + f;
    float v = agg[idx] / (denom[n0 + r] + 1e-16f) + bv;
    v = v > 0.f ? v : 0.f;
    out0[idx] = v;
    s1 += v; s2 += v * v;
  }
  __shared__ float red[256];
  red[threadIdx.x] = s1; __syncthreads();
  if (threadIdx.x < 128) atomicAdd(stats + f, red[threadIdx.x] + red[threadIdx.x + 128]);
  __syncthreads();
  red[threadIdx.x] = s2; __syncthreads();
  if (threadIdx.x < 128) atomicAdd(stats + HD + f, red[threadIdx.x] + red[threadIdx.x + 128]);
}

// ---- BN scale/shift from stats -----------------------------------------
__global__ void bn_params(const float* __restrict__ stats, const float* __restrict__ gamma,
                          const float* __restrict__ beta, float* __restrict__ scsh)
{
  const int f = threadIdx.x;
  const float inv_n = 1.f / (float)NNODE;
  const float mu  = stats[f] * inv_n;
  const float var = stats[HD + f] * inv_n - mu * mu;
  const float sc  = gamma[f] * rsqrtf(var + 1e-5f);
  scsh[f] = sc;
  scsh[HD + f] = beta[f] - mu * sc;
}

// ---- launch -------------------------------------------------------------
extern "C" void kernel_launch(void* const* d_in, const int* in_sizes, int n_in,
                              void* d_out, int out_size, void* d_ws, size_t ws_size,
                              hipStream_t stream) {
  const float* x        = (const float*)d_in[0];
  const int*   edge_raw = (const int*)  d_in[1];
  const float* conv1_w  = (const float*)d_in[2];
  const float* conv1_b  = (const float*)d_in[3];
  const float* Wl       = (const float*)d_in[4];
  const float* bl       = (const float*)d_in[5];
  const float* Wr       = (const float*)d_in[6];
  const float* br       = (const float*)d_in[7];
  const float* att      = (const float*)d_in[8];
  const float* gat_bias = (const float*)d_in[9];
  const float* bn_gamma = (const float*)d_in[10];
  const float* bn_beta  = (const float*)d_in[11];
  const float* conv2_w  = (const float*)d_in[12];
  const float* conv2_b  = (const float*)d_in[13];
  float* out = (float*)d_out;
  char*  ws  = (char*)d_ws;

  // d_out doubles as the conv1-output / GEMM-input buffer (dead until conv2's
  // final write). Workspace layout (bytes):
  const size_t o_xl   = 0;                        // NELEM f32 (xl; later GAT out)
  const size_t o_xr   = o_xl  + NELEM * 4;        // NELEM f32 (xr; later agg)
  const size_t o_e    = o_xr  + NELEM * 4;        // NTOT f32
  const size_t o_mk   = o_e   + (size_t)NTOT * 4; // NNODE u32
  const size_t o_den  = o_mk  + (size_t)NNODE * 4;// NNODE f32
  const size_t o_st   = o_den + (size_t)NNODE * 4;// 4*HD f32 (sum,sumsq,scale,shift)
  const size_t o_ed   = o_st  + 4 * HD * 4;       // 2*NE i32
  const size_t o_flag = o_ed  + (size_t)2 * NE * 4;

  float* h     = out;                             // conv1 out == n_feat flat view
  float* xl    = (float*)(ws + o_xl);
  float* xr    = (float*)(ws + o_xr);
  float* ebuf  = (float*)(ws + o_e);
  u32*   mkey  = (u32*)  (ws + o_mk);
  float* denom = (float*)(ws + o_den);
  float* stats = (float*)(ws + o_st);
  int*   ei32  = (int*)  (ws + o_ed);
  int*   flag  = (int*)  (ws + o_flag);

  hipMemsetAsync(mkey,  0, (size_t)NNODE * 4, stream);
  hipMemsetAsync(denom, 0, (size_t)NNODE * 4, stream);
  hipMemsetAsync(stats, 0, 2 * HD * 4, stream);

  detect_edges<<<1, 256, 0, stream>>>(edge_raw, flag);
  convert_edges<<<(2 * NE + 255) / 256, 256, 0, stream>>>(edge_raw, flag, ei32);

  // conv1 + relu -> h (=d_out)  (flat view == n_feat [NNODE, HD])
  conv_kernel<NCIN, false><<<dim3(NT / 128, HD / 32, NB), 256, 0, stream>>>(
      x, conv1_w, conv1_b, nullptr, nullptr, h);

  gemm_xlxr<<<NNODE / 64, 256, 0, stream>>>(h, Wl, bl, Wr, br, xl, xr);

  edge_score<<<(NTOT + 3) / 4, 256, 0, stream>>>(ei32, ei32 + NE, xl, xr, att, ebuf, mkey);

  // xr dead from here; reuse its region as the aggregation accumulator
  hipMemsetAsync(xr, 0, NELEM * 4, stream);
  edge_aggregate<<<(NTOT + 3) / 4, 256, 0, stream>>>(ei32, ei32 + NE, xl, ebuf, mkey, xr, denom);

  // xl dead from here; reuse as GAT output (pre-BN, relu'd, conv2 input)
  gat_finalize<<<NNODE / 64, 256, 0, stream>>>(xr, denom, gat_bias, xl, stats);

  bn_params<<<1, HD, 0, stream>>>(stats, bn_gamma, bn_beta, stats + 2 * HD);

  // conv2 with fused BN affine on load (note: BN feature index == t & 127)
  conv_kernel<HD, true><<<dim3(NT / 128, HD / 32, NB), 256, 0, stream>>>(
      xl, conv2_w, conv2_b, stats + 2 * HD, stats + 3 * HD, out);
}

// Round 3
// 1999.154 us; speedup vs baseline: 1.7174x; 1.7174x over previous
//
#include <hip/hip_runtime.h>

// ---- problem constants -------------------------------------------------
#define NB    128                 // batch
#define NCIN  64                  // conv1 in channels
#define NT    2048                // time
#define HD    128                 // hidden / heads*feat
#define NK    9                   // kernel size
#define NE    600000              // edges
#define NNODE (NB*NT)             // 262144 nodes
#define NTOT  (NE + NNODE)        // edges + self loops = 862144
static const size_t NELEM = (size_t)NNODE * HD;   // 33554432

typedef unsigned int u32;
typedef unsigned short ushort_t;
typedef __attribute__((ext_vector_type(8))) short short8;
typedef __attribute__((ext_vector_type(4))) float f32x4;

// fp32 -> bf16 (RNE), bit-level
__device__ __forceinline__ ushort_t f2b(float f) {
  u32 x = __float_as_uint(f);
  return (ushort_t)((x + 0x7fffu + ((x >> 16) & 1u)) >> 16);
}

// ordered-uint mapping for float atomic max
__device__ __forceinline__ u32 fkey(float f) {
  u32 b = __float_as_uint(f);
  return (b & 0x80000000u) ? ~b : (b | 0x80000000u);
}
__device__ __forceinline__ float funkey(u32 u) {
  u32 b = (u & 0x80000000u) ? (u & 0x7fffffffu) : ~u;
  return __uint_as_float(b);
}

// ---- edge index layout detection (int64 vs int32) ----------------------
__global__ __launch_bounds__(256) void detect_edges(const int* __restrict__ ebuf,
                                                    int* __restrict__ flag) {
  __shared__ int s;
  if (threadIdx.x == 0) s = 0;
  __syncthreads();
  int any = 0;
  for (int i = threadIdx.x; i < 512; i += 256)
    if (ebuf[2 * i + 1] != 0) any = 1;           // int64 LE -> high words are 0
  if (any) atomicOr(&s, 1);
  __syncthreads();
  if (threadIdx.x == 0) *flag = s;               // s!=0 -> buffer is int32
}

__global__ __launch_bounds__(256) void convert_edges(const int* __restrict__ ebuf,
                                                     const int* __restrict__ flag,
                                                     int* __restrict__ out) {
  int i = blockIdx.x * 256 + threadIdx.x;
  if (i >= 2 * NE) return;
  out[i] = (*flag) ? ebuf[i] : ebuf[2 * i];      // int64: take low word
}

// ---- conv weight transpose: w[o][ci][k] fp32 -> wt[k][o][ci] bf16 ------
__global__ __launch_bounds__(256) void conv_w_prep(const float* __restrict__ w,
                                                   ushort_t* __restrict__ wt,
                                                   int CI) {
  int idx = blockIdx.x * 256 + threadIdx.x;
  if (idx >= NK * HD * CI) return;
  const int ci = idx % CI;
  const int o  = (idx / CI) % HD;
  const int k  = idx / (CI * HD);
  wt[idx] = f2b(w[(o * CI + ci) * NK + k]);
}

// ---- conv1d SAME K=9 via MFMA implicit GEMM ----------------------------
// out[b][o][t] = relu(bias[o] + sum_{ci,k} w[o][ci][k] * aff(in[b][ci][t+k-4]))
// D[m=o][n=t]; A = Wb[k][o][ci] bf16 (global, L2-resident); B = input tile
// staged in LDS t-major [72][CI+8] bf16. Block tile: 128 o x 64 t, 4 waves.
template<int CI, bool AFFINE>
__global__ __launch_bounds__(256) void conv_mfma(
    const float* __restrict__ xin, const ushort_t* __restrict__ wtb,
    const float* __restrict__ bias, const float* __restrict__ scale,
    const float* __restrict__ shift, float* __restrict__ outp)
{
  constexpr int LDSW = CI + 8;                    // row stride (bf16 elems)
  constexpr int L2CI = (CI == 64) ? 6 : 7;
  const int t0 = blockIdx.x * 64;
  const int b  = blockIdx.y;
  __shared__ __align__(16) ushort_t xs[72 * LDSW];

  const int tid = threadIdx.x;
  const float* xb = xin + (size_t)b * CI * NT;

  // ---- stage input tile: t in [t0-4, t0+68), all CI channels ----
  for (int u = tid; u < CI * 18; u += 256) {
    const int ci = u & (CI - 1);
    const int tq = u >> L2CI;
    const int gt = t0 - 4 + tq * 4;
    float4 v = make_float4(0.f, 0.f, 0.f, 0.f);
    const float* src = xb + (size_t)ci * NT + gt;
    if (gt >= 0 && gt + 3 < NT) {
      v = *reinterpret_cast<const float4*>(src);
    } else {
      float* vp = &v.x;
      #pragma unroll
      for (int e = 0; e < 4; ++e) {
        const int g = gt + e;
        if (g >= 0 && g < NT) vp[e] = src[e];
      }
    }
    float* vp = &v.x;
    #pragma unroll
    for (int e = 0; e < 4; ++e) {
      float val = vp[e];
      if (AFFINE) {
        const int g = gt + e;
        if (g >= 0 && g < NT) val = val * scale[g & 127] + shift[g & 127];
      }
      xs[(tq * 4 + e) * LDSW + ci] = f2b(val);
    }
  }
  __syncthreads();

  // ---- MFMA main loop ----
  const int lane = tid & 63;
  const int wid  = tid >> 6;
  const int wo   = wid >> 1;                      // o half (64)
  const int wt   = wid & 1;                       // t half (32)
  const int l15  = lane & 15;
  const int lk   = lane >> 4;                     // k-chunk 0..3

  f32x4 acc[4][2];
  #pragma unroll
  for (int mr = 0; mr < 4; ++mr)
    #pragma unroll
    for (int nr = 0; nr < 2; ++nr) acc[mr][nr] = (f32x4){0.f, 0.f, 0.f, 0.f};

  const ushort_t* wbase = wtb + (size_t)(wo * 64 + l15) * CI + lk * 8;

  for (int k = 0; k < NK; ++k) {
    const ushort_t* wk = wbase + (size_t)k * HD * CI;
    #pragma unroll
    for (int cc = 0; cc < CI / 32; ++cc) {
      short8 bfr[2];
      #pragma unroll
      for (int nr = 0; nr < 2; ++nr)
        bfr[nr] = *reinterpret_cast<const short8*>(
            &xs[(wt * 32 + nr * 16 + l15 + k) * LDSW + cc * 32 + lk * 8]);
      #pragma unroll
      for (int mr = 0; mr < 4; ++mr) {
        const short8 afr = *reinterpret_cast<const short8*>(wk + mr * 16 * CI + cc * 32);
        #pragma unroll
        for (int nr = 0; nr < 2; ++nr)
          acc[mr][nr] = __builtin_amdgcn_mfma_f32_16x16x32_bf16(afr, bfr[nr], acc[mr][nr], 0, 0, 0);
      }
    }
  }

  // ---- epilogue: bias + relu, coalesced dword stores along t ----
  const int tcol = t0 + wt * 32 + l15;            // + nr*16
  #pragma unroll
  for (int mr = 0; mr < 4; ++mr) {
    #pragma unroll
    for (int e = 0; e < 4; ++e) {
      const int o = wo * 64 + mr * 16 + lk * 4 + e;
      const float bv = bias[o];
      float* orow = outp + ((size_t)b * HD + o) * NT;
      #pragma unroll
      for (int nr = 0; nr < 2; ++nr) {
        float v = acc[mr][nr][e] + bv;
        orow[tcol + nr * 16] = v > 0.f ? v : 0.f;
      }
    }
  }
}

// ---- fused xl = nf@Wl.T+bl, xr = nf@Wr.T+br ----------------------------
__global__ __launch_bounds__(256) void gemm_xlxr(
    const float* __restrict__ nf, const float* __restrict__ Wl,
    const float* __restrict__ bl, const float* __restrict__ Wr,
    const float* __restrict__ br, float* __restrict__ xl, float* __restrict__ xr)
{
  const int n0 = blockIdx.x * 64;
  __shared__ float nfs[64][17];
  __shared__ float wls[128][17];
  __shared__ float wrs[128][17];
  const int tid = threadIdx.x;
  const int tn = tid & 15;                       // 16 groups * 4 rows
  const int tj = tid >> 4;                       // 16 groups * 8 cols
  float accl[4][8] = {}, accr[4][8] = {};
  for (int f0 = 0; f0 < HD; f0 += 16) {
    for (int i = tid; i < 64 * 16; i += 256) {
      const int r = i >> 4, c = i & 15;
      nfs[r][c] = nf[(size_t)(n0 + r) * HD + f0 + c];
    }
    for (int i = tid; i < 128 * 16; i += 256) {
      const int r = i >> 4, c = i & 15;
      wls[r][c] = Wl[r * HD + f0 + c];
      wrs[r][c] = Wr[r * HD + f0 + c];
    }
    __syncthreads();
    #pragma unroll
    for (int k = 0; k < 16; ++k) {
      float a[4], wl8[8], wr8[8];
      #pragma unroll
      for (int i = 0; i < 4; ++i) a[i] = nfs[tn * 4 + i][k];
      #pragma unroll
      for (int j = 0; j < 8; ++j) { wl8[j] = wls[tj * 8 + j][k]; wr8[j] = wrs[tj * 8 + j][k]; }
      #pragma unroll
      for (int i = 0; i < 4; ++i)
        #pragma unroll
        for (int j = 0; j < 8; ++j) { accl[i][j] += a[i] * wl8[j]; accr[i][j] += a[i] * wr8[j]; }
    }
    __syncthreads();
  }
  #pragma unroll
  for (int i = 0; i < 4; ++i) {
    const size_t row = (size_t)(n0 + tn * 4 + i) * HD;
    #pragma unroll
    for (int j = 0; j < 8; ++j) {
      const int col = tj * 8 + j;
      xl[row + col] = accl[i][j] + bl[col];
      xr[row + col] = accr[i][j] + br[col];
    }
  }
}

// ---- per-edge attention score + segment max ----------------------------
__global__ __launch_bounds__(256) void edge_score(
    const int* __restrict__ esrc, const int* __restrict__ edst,
    const float* __restrict__ xl, const float* __restrict__ xr,
    const float* __restrict__ att, float* __restrict__ ebuf, u32* __restrict__ mkey)
{
  const int eid = blockIdx.x * 4 + (threadIdx.x >> 6);
  const int lane = threadIdx.x & 63;
  if (eid >= NTOT) return;
  int s_, d_;
  if (eid < NE) { s_ = esrc[eid]; d_ = edst[eid]; } else { s_ = d_ = eid - NE; }
  const float* xls = xl + (size_t)s_ * HD;
  const float* xrd = xr + (size_t)d_ * HD;
  float v = 0.f;
  #pragma unroll
  for (int f = lane; f < HD; f += 64) {
    float q = xls[f] + xrd[f];
    q = q > 0.f ? q : 0.2f * q;
    v += att[f] * q;
  }
  #pragma unroll
  for (int off = 32; off > 0; off >>= 1) v += __shfl_xor(v, off);
  if (lane == 0) { ebuf[eid] = v; atomicMax(mkey + d_, fkey(v)); }
}

// ---- exp/softmax-denominator + weighted message aggregation ------------
__global__ __launch_bounds__(256) void edge_aggregate(
    const int* __restrict__ esrc, const int* __restrict__ edst,
    const float* __restrict__ xl, const float* __restrict__ ebuf,
    const u32* __restrict__ mkey, float* __restrict__ agg, float* __restrict__ denom)
{
  const int eid = blockIdx.x * 4 + (threadIdx.x >> 6);
  const int lane = threadIdx.x & 63;
  if (eid >= NTOT) return;
  int s_, d_;
  if (eid < NE) { s_ = esrc[eid]; d_ = edst[eid]; } else { s_ = d_ = eid - NE; }
  const float a = expf(ebuf[eid] - funkey(mkey[d_]));
  if (lane == 0) atomicAdd(denom + d_, a);
  const float* xls = xl + (size_t)s_ * HD;
  float* ag = agg + (size_t)d_ * HD;
  atomicAdd(ag + lane,      a * xls[lane]);
  atomicAdd(ag + lane + 64, a * xls[lane + 64]);
}

// ---- finalize GAT (div, bias, relu) + BN statistics --------------------
__global__ __launch_bounds__(256) void gat_finalize(
    const float* __restrict__ agg, const float* __restrict__ denom,
    const float* __restrict__ gbias, float* __restrict__ out0, float* __restrict__ stats)
{
  const int n0 = blockIdx.x * 64;
  const int f  = threadIdx.x & 127;
  const int rh = threadIdx.x >> 7;
  const float bv = gbias[f];
  float s1 = 0.f, s2 = 0.f;
  for (int r = rh; r < 64; r += 2) {
    const size_t idx = (size_t)(n0 + r) * HD + f;
    float v = agg[idx] / (denom[n0 + r] + 1e-16f) + bv;
    v = v > 0.f ? v : 0.f;
    out0[idx] = v;
    s1 += v; s2 += v * v;
  }
  __shared__ float red[256];
  red[threadIdx.x] = s1; __syncthreads();
  if (threadIdx.x < 128) atomicAdd(stats + f, red[threadIdx.x] + red[threadIdx.x + 128]);
  __syncthreads();
  red[threadIdx.x] = s2; __syncthreads();
  if (threadIdx.x < 128) atomicAdd(stats + HD + f, red[threadIdx.x] + red[threadIdx.x + 128]);
}

// ---- BN scale/shift from stats -----------------------------------------
__global__ void bn_params(const float* __restrict__ stats, const float* __restrict__ gamma,
                          const float* __restrict__ beta, float* __restrict__ scsh)
{
  const int f = threadIdx.x;
  const float inv_n = 1.f / (float)NNODE;
  const float mu  = stats[f] * inv_n;
  const float var = stats[HD + f] * inv_n - mu * mu;
  const float sc  = gamma[f] * rsqrtf(var + 1e-5f);
  scsh[f] = sc;
  scsh[HD + f] = beta[f] - mu * sc;
}

// ---- launch -------------------------------------------------------------
extern "C" void kernel_launch(void* const* d_in, const int* in_sizes, int n_in,
                              void* d_out, int out_size, void* d_ws, size_t ws_size,
                              hipStream_t stream) {
  const float* x        = (const float*)d_in[0];
  const int*   edge_raw = (const int*)  d_in[1];
  const float* conv1_w  = (const float*)d_in[2];
  const float* conv1_b  = (const float*)d_in[3];
  const float* Wl       = (const float*)d_in[4];
  const float* bl       = (const float*)d_in[5];
  const float* Wr       = (const float*)d_in[6];
  const float* br       = (const float*)d_in[7];
  const float* att      = (const float*)d_in[8];
  const float* gat_bias = (const float*)d_in[9];
  const float* bn_gamma = (const float*)d_in[10];
  const float* bn_beta  = (const float*)d_in[11];
  const float* conv2_w  = (const float*)d_in[12];
  const float* conv2_b  = (const float*)d_in[13];
  float* out = (float*)d_out;
  char*  ws  = (char*)d_ws;

  // d_out doubles as the conv1-output / GEMM-input buffer (dead until conv2's
  // final write). Workspace layout (bytes):
  const size_t o_xl   = 0;                        // NELEM f32 (xl; later GAT out)
  const size_t o_xr   = o_xl  + NELEM * 4;        // NELEM f32 (xr; later agg)
  const size_t o_e    = o_xr  + NELEM * 4;        // NTOT f32
  const size_t o_mk   = o_e   + (size_t)NTOT * 4; // NNODE u32
  const size_t o_den  = o_mk  + (size_t)NNODE * 4;// NNODE f32
  const size_t o_st   = o_den + (size_t)NNODE * 4;// 4*HD f32 (sum,sumsq,scale,shift)
  const size_t o_ed   = o_st  + 4 * HD * 4;       // 2*NE i32
  const size_t o_flag = o_ed  + (size_t)2 * NE * 4;
  const size_t o_w1   = (o_flag + 64) & ~(size_t)63;   // 9*128*64 bf16
  const size_t o_w2   = o_w1 + (size_t)NK * HD * NCIN * 2; // 9*128*128 bf16

  float* h     = out;                             // conv1 out == n_feat flat view
  float* xl    = (float*)(ws + o_xl);
  float* xr    = (float*)(ws + o_xr);
  float* ebuf  = (float*)(ws + o_e);
  u32*   mkey  = (u32*)  (ws + o_mk);
  float* denom = (float*)(ws + o_den);
  float* stats = (float*)(ws + o_st);
  int*   ei32  = (int*)  (ws + o_ed);
  int*   flag  = (int*)  (ws + o_flag);
  ushort_t* w1b = (ushort_t*)(ws + o_w1);
  ushort_t* w2b = (ushort_t*)(ws + o_w2);

  hipMemsetAsync(mkey,  0, (size_t)NNODE * 4, stream);
  hipMemsetAsync(denom, 0, (size_t)NNODE * 4, stream);
  hipMemsetAsync(stats, 0, 2 * HD * 4, stream);

  detect_edges<<<1, 256, 0, stream>>>(edge_raw, flag);
  convert_edges<<<(2 * NE + 255) / 256, 256, 0, stream>>>(edge_raw, flag, ei32);

  conv_w_prep<<<(NK * HD * NCIN + 255) / 256, 256, 0, stream>>>(conv1_w, w1b, NCIN);
  conv_w_prep<<<(NK * HD * HD + 255) / 256, 256, 0, stream>>>(conv2_w, w2b, HD);

  // conv1 + relu -> h (=d_out)  (flat view == n_feat [NNODE, HD])
  conv_mfma<NCIN, false><<<dim3(NT / 64, NB), 256, 0, stream>>>(
      x, w1b, conv1_b, nullptr, nullptr, h);

  gemm_xlxr<<<NNODE / 64, 256, 0, stream>>>(h, Wl, bl, Wr, br, xl, xr);

  edge_score<<<(NTOT + 3) / 4, 256, 0, stream>>>(ei32, ei32 + NE, xl, xr, att, ebuf, mkey);

  // xr dead from here; reuse its region as the aggregation accumulator
  hipMemsetAsync(xr, 0, NELEM * 4, stream);
  edge_aggregate<<<(NTOT + 3) / 4, 256, 0, stream>>>(ei32, ei32 + NE, xl, ebuf, mkey, xr, denom);

  // xl dead from here; reuse as GAT output (pre-BN, relu'd, conv2 input)
  gat_finalize<<<NNODE / 64, 256, 0, stream>>>(xr, denom, gat_bias, xl, stats);

  bn_params<<<1, HD, 0, stream>>>(stats, bn_gamma, bn_beta, stats + 2 * HD);

  // conv2 with fused BN affine on stage (note: BN feature index == t & 127)
  conv_mfma<HD, true><<<dim3(NT / 64, NB), 256, 0, stream>>>(
      xl, w2b, conv2_b, stats + 2 * HD, stats + 3 * HD, out);
}

// Round 4
// 1599.913 us; speedup vs baseline: 2.1460x; 1.2495x over previous
//
#include <hip/hip_runtime.h>

// ---- problem constants -------------------------------------------------
#define NB    128                 // batch
#define NCIN  64                  // conv1 in channels
#define NT    2048                // time
#define HD    128                 // hidden / heads*feat
#define NK    9                   // kernel size
#define NE    600000              // edges
#define NNODE (NB*NT)             // 262144 nodes
#define NTOT  (NE + NNODE)        // edges + self loops = 862144
static const size_t NELEM = (size_t)NNODE * HD;   // 33554432

typedef unsigned int u32;
typedef unsigned short ushort_t;
typedef __attribute__((ext_vector_type(8))) short short8;
typedef __attribute__((ext_vector_type(4))) float f32x4;

// fp32 -> bf16 (RNE), bit-level
__device__ __forceinline__ ushort_t f2b(float f) {
  u32 x = __float_as_uint(f);
  return (ushort_t)((x + 0x7fffu + ((x >> 16) & 1u)) >> 16);
}

// ordered-uint mapping for float atomic max
__device__ __forceinline__ u32 fkey(float f) {
  u32 b = __float_as_uint(f);
  return (b & 0x80000000u) ? ~b : (b | 0x80000000u);
}
__device__ __forceinline__ float funkey(u32 u) {
  u32 b = (u & 0x80000000u) ? (u & 0x7fffffffu) : ~u;
  return __uint_as_float(b);
}

// ---- edge index layout detection (int64 vs int32) ----------------------
__global__ __launch_bounds__(256) void detect_edges(const int* __restrict__ ebuf,
                                                    int* __restrict__ flag) {
  __shared__ int s;
  if (threadIdx.x == 0) s = 0;
  __syncthreads();
  int any = 0;
  for (int i = threadIdx.x; i < 512; i += 256)
    if (ebuf[2 * i + 1] != 0) any = 1;           // int64 LE -> high words are 0
  if (any) atomicOr(&s, 1);
  __syncthreads();
  if (threadIdx.x == 0) *flag = s;               // s!=0 -> buffer is int32
}

__global__ __launch_bounds__(256) void convert_edges(const int* __restrict__ ebuf,
                                                     const int* __restrict__ flag,
                                                     int* __restrict__ out) {
  int i = blockIdx.x * 256 + threadIdx.x;
  if (i >= 2 * NE) return;
  out[i] = (*flag) ? ebuf[i] : ebuf[2 * i];      // int64: take low word
}

// ---- conv weight transpose: w[o][ci][k] fp32 -> wt[k][o][ci] bf16 ------
__global__ __launch_bounds__(256) void conv_w_prep(const float* __restrict__ w,
                                                   ushort_t* __restrict__ wt,
                                                   int CI) {
  int idx = blockIdx.x * 256 + threadIdx.x;
  if (idx >= NK * HD * CI) return;
  const int ci = idx % CI;
  const int o  = (idx / CI) % HD;
  const int k  = idx / (CI * HD);
  wt[idx] = f2b(w[(o * CI + ci) * NK + k]);
}

// ---- Wl/Wr fp32 -> bf16 (row-major [out][in] kept) ---------------------
__global__ __launch_bounds__(256) void wlr_prep(const float* __restrict__ Wl,
                                                const float* __restrict__ Wr,
                                                ushort_t* __restrict__ wb) {
  int i = blockIdx.x * 256 + threadIdx.x;
  if (i >= HD * HD) return;
  wb[i] = f2b(Wl[i]);
  wb[HD * HD + i] = f2b(Wr[i]);
}

// ---- conv1d SAME K=9 via MFMA implicit GEMM ----------------------------
template<int CI, bool AFFINE>
__global__ __launch_bounds__(256) void conv_mfma(
    const float* __restrict__ xin, const ushort_t* __restrict__ wtb,
    const float* __restrict__ bias, const float* __restrict__ scale,
    const float* __restrict__ shift, float* __restrict__ outp)
{
  constexpr int LDSW = CI + 8;                    // row stride (bf16 elems)
  constexpr int L2CI = (CI == 64) ? 6 : 7;
  const int t0 = blockIdx.x * 64;
  const int b  = blockIdx.y;
  __shared__ __align__(16) ushort_t xs[72 * LDSW];

  const int tid = threadIdx.x;
  const float* xb = xin + (size_t)b * CI * NT;

  // ---- stage input tile: t in [t0-4, t0+68), all CI channels ----
  for (int u = tid; u < CI * 18; u += 256) {
    const int ci = u & (CI - 1);
    const int tq = u >> L2CI;
    const int gt = t0 - 4 + tq * 4;
    float4 v = make_float4(0.f, 0.f, 0.f, 0.f);
    const float* src = xb + (size_t)ci * NT + gt;
    if (gt >= 0 && gt + 3 < NT) {
      v = *reinterpret_cast<const float4*>(src);
    } else {
      float* vp = &v.x;
      #pragma unroll
      for (int e = 0; e < 4; ++e) {
        const int g = gt + e;
        if (g >= 0 && g < NT) vp[e] = src[e];
      }
    }
    float* vp = &v.x;
    #pragma unroll
    for (int e = 0; e < 4; ++e) {
      float val = vp[e];
      if (AFFINE) {
        const int g = gt + e;
        if (g >= 0 && g < NT) val = val * scale[g & 127] + shift[g & 127];
      }
      xs[(tq * 4 + e) * LDSW + ci] = f2b(val);
    }
  }
  __syncthreads();

  // ---- MFMA main loop ----
  const int lane = tid & 63;
  const int wid  = tid >> 6;
  const int wo   = wid >> 1;                      // o half (64)
  const int wt   = wid & 1;                       // t half (32)
  const int l15  = lane & 15;
  const int lk   = lane >> 4;                     // k-chunk 0..3

  f32x4 acc[4][2];
  #pragma unroll
  for (int mr = 0; mr < 4; ++mr)
    #pragma unroll
    for (int nr = 0; nr < 2; ++nr) acc[mr][nr] = (f32x4){0.f, 0.f, 0.f, 0.f};

  const ushort_t* wbase = wtb + (size_t)(wo * 64 + l15) * CI + lk * 8;

  for (int k = 0; k < NK; ++k) {
    const ushort_t* wk = wbase + (size_t)k * HD * CI;
    #pragma unroll
    for (int cc = 0; cc < CI / 32; ++cc) {
      short8 bfr[2];
      #pragma unroll
      for (int nr = 0; nr < 2; ++nr)
        bfr[nr] = *reinterpret_cast<const short8*>(
            &xs[(wt * 32 + nr * 16 + l15 + k) * LDSW + cc * 32 + lk * 8]);
      #pragma unroll
      for (int mr = 0; mr < 4; ++mr) {
        const short8 afr = *reinterpret_cast<const short8*>(wk + mr * 16 * CI + cc * 32);
        #pragma unroll
        for (int nr = 0; nr < 2; ++nr)
          acc[mr][nr] = __builtin_amdgcn_mfma_f32_16x16x32_bf16(afr, bfr[nr], acc[mr][nr], 0, 0, 0);
      }
    }
  }

  // ---- epilogue: bias + relu, coalesced dword stores along t ----
  const int tcol = t0 + wt * 32 + l15;            // + nr*16
  #pragma unroll
  for (int mr = 0; mr < 4; ++mr) {
    #pragma unroll
    for (int e = 0; e < 4; ++e) {
      const int o = wo * 64 + mr * 16 + lk * 4 + e;
      const float bv = bias[o];
      float* orow = outp + ((size_t)b * HD + o) * NT;
      #pragma unroll
      for (int nr = 0; nr < 2; ++nr) {
        float v = acc[mr][nr][e] + bv;
        orow[tcol + nr * 16] = v > 0.f ? v : 0.f;
      }
    }
  }
}

// ---- fused xl/xr GEMM via MFMA: xl = nf@Wl.T+bl, xr = nf@Wr.T+br -------
// D[m=node][n=feat]; A = nf tile (LDS bf16, padded), B = wb (bf16 global,
// row-major [out][in] == B-frag [n][k] contiguous). 64 nodes/block, 4 waves.
__global__ __launch_bounds__(256) void gemm_xlxr_mfma(
    const float* __restrict__ nf, const ushort_t* __restrict__ wb,
    const float* __restrict__ bl, const float* __restrict__ br,
    float* __restrict__ xl, float* __restrict__ xr)
{
  const int n0 = blockIdx.x * 64;
  __shared__ __align__(16) ushort_t nfs[64 * 136];   // 64 rows x (128+8) bf16
  const int tid = threadIdx.x;

  // stage 64x128 fp32 -> bf16 (coalesced 32B/thread)
  for (int u = tid; u < 64 * 16; u += 256) {
    const int r = u >> 4, c8 = (u & 15) * 8;
    const float* src = nf + (size_t)(n0 + r) * HD + c8;
    const float4 v0 = *reinterpret_cast<const float4*>(src);
    const float4 v1 = *reinterpret_cast<const float4*>(src + 4);
    ushort_t tmp[8] = {f2b(v0.x), f2b(v0.y), f2b(v0.z), f2b(v0.w),
                       f2b(v1.x), f2b(v1.y), f2b(v1.z), f2b(v1.w)};
    *reinterpret_cast<short8*>(&nfs[r * 136 + c8]) = *reinterpret_cast<const short8*>(tmp);
  }
  __syncthreads();

  const int lane = tid & 63;
  const int wid  = tid >> 6;                      // wave owns nodes wid*16..+16
  const int l15  = lane & 15;
  const int lk   = lane >> 4;

  f32x4 accl[8], accr[8];
  #pragma unroll
  for (int nt = 0; nt < 8; ++nt) {
    accl[nt] = (f32x4){0.f, 0.f, 0.f, 0.f};
    accr[nt] = (f32x4){0.f, 0.f, 0.f, 0.f};
  }

  #pragma unroll
  for (int kc = 0; kc < 4; ++kc) {
    const short8 afr = *reinterpret_cast<const short8*>(
        &nfs[(wid * 16 + l15) * 136 + kc * 32 + lk * 8]);
    const ushort_t* wrow = wb + (size_t)l15 * HD + kc * 32 + lk * 8;
    #pragma unroll
    for (int nt = 0; nt < 8; ++nt) {
      const short8 bfl = *reinterpret_cast<const short8*>(wrow + nt * 16 * HD);
      const short8 bfr = *reinterpret_cast<const short8*>(wrow + HD * HD + nt * 16 * HD);
      accl[nt] = __builtin_amdgcn_mfma_f32_16x16x32_bf16(afr, bfl, accl[nt], 0, 0, 0);
      accr[nt] = __builtin_amdgcn_mfma_f32_16x16x32_bf16(afr, bfr, accr[nt], 0, 0, 0);
    }
  }

  #pragma unroll
  for (int nt = 0; nt < 8; ++nt) {
    const int feat = nt * 16 + l15;
    const float bvl = bl[feat], bvr = br[feat];
    #pragma unroll
    for (int e = 0; e < 4; ++e) {
      const size_t row = (size_t)(n0 + wid * 16 + lk * 4 + e) * HD;
      xl[row + feat] = accl[nt][e] + bvl;
      xr[row + feat] = accr[nt][e] + bvr;
    }
  }
}

// ---- per-edge attention score + segment max ----------------------------
__global__ __launch_bounds__(256) void edge_score(
    const int* __restrict__ esrc, const int* __restrict__ edst,
    const float* __restrict__ xl, const float* __restrict__ xr,
    const float* __restrict__ att, float* __restrict__ ebuf, u32* __restrict__ mkey)
{
  const int eid = blockIdx.x * 4 + (threadIdx.x >> 6);
  const int lane = threadIdx.x & 63;
  if (eid >= NTOT) return;
  int s_, d_;
  if (eid < NE) { s_ = esrc[eid]; d_ = edst[eid]; } else { s_ = d_ = eid - NE; }
  const float* xls = xl + (size_t)s_ * HD;
  const float* xrd = xr + (size_t)d_ * HD;
  float v = 0.f;
  #pragma unroll
  for (int f = lane; f < HD; f += 64) {
    float q = xls[f] + xrd[f];
    q = q > 0.f ? q : 0.2f * q;
    v += att[f] * q;
  }
  #pragma unroll
  for (int off = 32; off > 0; off >>= 1) v += __shfl_xor(v, off);
  if (lane == 0) { ebuf[eid] = v; atomicMax(mkey + d_, fkey(v)); }
}

// ---- exp/softmax-denominator + weighted message aggregation ------------
__global__ __launch_bounds__(256) void edge_aggregate(
    const int* __restrict__ esrc, const int* __restrict__ edst,
    const float* __restrict__ xl, const float* __restrict__ ebuf,
    const u32* __restrict__ mkey, float* __restrict__ agg, float* __restrict__ denom)
{
  const int eid = blockIdx.x * 4 + (threadIdx.x >> 6);
  const int lane = threadIdx.x & 63;
  if (eid >= NTOT) return;
  int s_, d_;
  if (eid < NE) { s_ = esrc[eid]; d_ = edst[eid]; } else { s_ = d_ = eid - NE; }
  const float a = expf(ebuf[eid] - funkey(mkey[d_]));
  if (lane == 0) atomicAdd(denom + d_, a);
  const float* xls = xl + (size_t)s_ * HD;
  float* ag = agg + (size_t)d_ * HD;
  atomicAdd(ag + lane,      a * xls[lane]);
  atomicAdd(ag + lane + 64, a * xls[lane + 64]);
}

// ---- finalize GAT (div, bias, relu) + BN statistics --------------------
__global__ __launch_bounds__(256) void gat_finalize(
    const float* __restrict__ agg, const float* __restrict__ denom,
    const float* __restrict__ gbias, float* __restrict__ out0, float* __restrict__ stats)
{
  const int n0 = blockIdx.x * 64;
  const int f  = threadIdx.x & 127;
  const int rh = threadIdx.x >> 7;
  const float bv = gbias[f];
  float s1 = 0.f, s2 = 0.f;
  for (int r = rh; r < 64; r += 2) {
    const size_t idx = (size_t)(n0 + r) * HD + f;
    float v = agg[idx] / (denom[n0 + r] + 1e-16f) + bv;
    v = v > 0.f ? v : 0.f;
    out0[idx] = v;
    s1 += v; s2 += v * v;
  }
  __shared__ float red[256];
  red[threadIdx.x] = s1; __syncthreads();
  if (threadIdx.x < 128) atomicAdd(stats + f, red[threadIdx.x] + red[threadIdx.x + 128]);
  __syncthreads();
  red[threadIdx.x] = s2; __syncthreads();
  if (threadIdx.x < 128) atomicAdd(stats + HD + f, red[threadIdx.x] + red[threadIdx.x + 128]);
}

// ---- BN scale/shift from stats -----------------------------------------
__global__ void bn_params(const float* __restrict__ stats, const float* __restrict__ gamma,
                          const float* __restrict__ beta, float* __restrict__ scsh)
{
  const int f = threadIdx.x;
  const float inv_n = 1.f / (float)NNODE;
  const float mu  = stats[f] * inv_n;
  const float var = stats[HD + f] * inv_n - mu * mu;
  const float sc  = gamma[f] * rsqrtf(var + 1e-5f);
  scsh[f] = sc;
  scsh[HD + f] = beta[f] - mu * sc;
}

// ---- launch -------------------------------------------------------------
extern "C" void kernel_launch(void* const* d_in, const int* in_sizes, int n_in,
                              void* d_out, int out_size, void* d_ws, size_t ws_size,
                              hipStream_t stream) {
  const float* x        = (const float*)d_in[0];
  const int*   edge_raw = (const int*)  d_in[1];
  const float* conv1_w  = (const float*)d_in[2];
  const float* conv1_b  = (const float*)d_in[3];
  const float* Wl       = (const float*)d_in[4];
  const float* bl       = (const float*)d_in[5];
  const float* Wr       = (const float*)d_in[6];
  const float* br       = (const float*)d_in[7];
  const float* att      = (const float*)d_in[8];
  const float* gat_bias = (const float*)d_in[9];
  const float* bn_gamma = (const float*)d_in[10];
  const float* bn_beta  = (const float*)d_in[11];
  const float* conv2_w  = (const float*)d_in[12];
  const float* conv2_b  = (const float*)d_in[13];
  float* out = (float*)d_out;
  char*  ws  = (char*)d_ws;

  // d_out doubles as the conv1-output / GEMM-input buffer (dead until conv2's
  // final write). Workspace layout (bytes):
  const size_t o_xl   = 0;                        // NELEM f32 (xl; later GAT out)
  const size_t o_xr   = o_xl  + NELEM * 4;        // NELEM f32 (xr; later agg)
  const size_t o_e    = o_xr  + NELEM * 4;        // NTOT f32
  const size_t o_mk   = o_e   + (size_t)NTOT * 4; // NNODE u32
  const size_t o_den  = o_mk  + (size_t)NNODE * 4;// NNODE f32
  const size_t o_st   = o_den + (size_t)NNODE * 4;// 4*HD f32 (sum,sumsq,scale,shift)
  const size_t o_ed   = o_st  + 4 * HD * 4;       // 2*NE i32
  const size_t o_flag = o_ed  + (size_t)2 * NE * 4;
  const size_t o_w1   = (o_flag + 64) & ~(size_t)63;        // 9*128*64 bf16
  const size_t o_w2   = o_w1 + (size_t)NK * HD * NCIN * 2;  // 9*128*128 bf16
  const size_t o_wlr  = o_w2 + (size_t)NK * HD * HD * 2;    // 2*128*128 bf16

  float* h     = out;                             // conv1 out == n_feat flat view
  float* xl    = (float*)(ws + o_xl);
  float* xr    = (float*)(ws + o_xr);
  float* ebuf  = (float*)(ws + o_e);
  u32*   mkey  = (u32*)  (ws + o_mk);
  float* denom = (float*)(ws + o_den);
  float* stats = (float*)(ws + o_st);
  int*   ei32  = (int*)  (ws + o_ed);
  int*   flag  = (int*)  (ws + o_flag);
  ushort_t* w1b  = (ushort_t*)(ws + o_w1);
  ushort_t* w2b  = (ushort_t*)(ws + o_w2);
  ushort_t* wlrb = (ushort_t*)(ws + o_wlr);

  hipMemsetAsync(mkey,  0, (size_t)NNODE * 4, stream);
  hipMemsetAsync(denom, 0, (size_t)NNODE * 4, stream);
  hipMemsetAsync(stats, 0, 2 * HD * 4, stream);

  detect_edges<<<1, 256, 0, stream>>>(edge_raw, flag);
  convert_edges<<<(2 * NE + 255) / 256, 256, 0, stream>>>(edge_raw, flag, ei32);

  conv_w_prep<<<(NK * HD * NCIN + 255) / 256, 256, 0, stream>>>(conv1_w, w1b, NCIN);
  conv_w_prep<<<(NK * HD * HD + 255) / 256, 256, 0, stream>>>(conv2_w, w2b, HD);
  wlr_prep<<<(HD * HD + 255) / 256, 256, 0, stream>>>(Wl, Wr, wlrb);

  // conv1 + relu -> h (=d_out)  (flat view == n_feat [NNODE, HD])
  conv_mfma<NCIN, false><<<dim3(NT / 64, NB), 256, 0, stream>>>(
      x, w1b, conv1_b, nullptr, nullptr, h);

  gemm_xlxr_mfma<<<NNODE / 64, 256, 0, stream>>>(h, wlrb, bl, br, xl, xr);

  edge_score<<<(NTOT + 3) / 4, 256, 0, stream>>>(ei32, ei32 + NE, xl, xr, att, ebuf, mkey);

  // xr dead from here; reuse its region as the aggregation accumulator
  hipMemsetAsync(xr, 0, NELEM * 4, stream);
  edge_aggregate<<<(NTOT + 3) / 4, 256, 0, stream>>>(ei32, ei32 + NE, xl, ebuf, mkey, xr, denom);

  // xl dead from here; reuse as GAT output (pre-BN, relu'd, conv2 input)
  gat_finalize<<<NNODE / 64, 256, 0, stream>>>(xr, denom, gat_bias, xl, stats);

  bn_params<<<1, HD, 0, stream>>>(stats, bn_gamma, bn_beta, stats + 2 * HD);

  // conv2 with fused BN affine on stage (note: BN feature index == t & 127)
  conv_mfma<HD, true><<<dim3(NT / 64, NB), 256, 0, stream>>>(
      xl, w2b, conv2_b, stats + 2 * HD, stats + 3 * HD, out);
}

// Round 5
// 1171.669 us; speedup vs baseline: 2.9303x; 1.3655x over previous
//
#include <hip/hip_runtime.h>

// ---- problem constants -------------------------------------------------
#define NB    128                 // batch
#define NCIN  64                  // conv1 in channels
#define NT    2048                // time
#define HD    128                 // hidden / heads*feat
#define NK    9                   // kernel size
#define NE    600000              // edges
#define NNODE (NB*NT)             // 262144 nodes
#define NTOT  (NE + NNODE)        // edges + self loops = 862144
static const size_t NELEM = (size_t)NNODE * HD;   // 33554432

typedef unsigned int u32;
typedef unsigned short ushort_t;
typedef __attribute__((ext_vector_type(8))) short short8;
typedef __attribute__((ext_vector_type(4))) float f32x4;

// fp32 -> bf16 (RNE), bit-level
__device__ __forceinline__ ushort_t f2b(float f) {
  u32 x = __float_as_uint(f);
  return (ushort_t)((x + 0x7fffu + ((x >> 16) & 1u)) >> 16);
}

// ---- edge index layout detection (int64 vs int32) ----------------------
__global__ __launch_bounds__(256) void detect_edges(const int* __restrict__ ebuf,
                                                    int* __restrict__ flag) {
  __shared__ int s;
  if (threadIdx.x == 0) s = 0;
  __syncthreads();
  int any = 0;
  for (int i = threadIdx.x; i < 512; i += 256)
    if (ebuf[2 * i + 1] != 0) any = 1;           // int64 LE -> high words are 0
  if (any) atomicOr(&s, 1);
  __syncthreads();
  if (threadIdx.x == 0) *flag = s;               // s!=0 -> buffer is int32
}

__global__ __launch_bounds__(256) void convert_edges(const int* __restrict__ ebuf,
                                                     const int* __restrict__ flag,
                                                     int* __restrict__ out) {
  int i = blockIdx.x * 256 + threadIdx.x;
  if (i >= 2 * NE) return;
  out[i] = (*flag) ? ebuf[i] : ebuf[2 * i];      // int64: take low word
}

// ---- conv weight transpose: w[o][ci][k] fp32 -> wt[k][o][ci] bf16 ------
__global__ __launch_bounds__(256) void conv_w_prep(const float* __restrict__ w,
                                                   ushort_t* __restrict__ wt,
                                                   int CI) {
  int idx = blockIdx.x * 256 + threadIdx.x;
  if (idx >= NK * HD * CI) return;
  const int ci = idx % CI;
  const int o  = (idx / CI) % HD;
  const int k  = idx / (CI * HD);
  wt[idx] = f2b(w[(o * CI + ci) * NK + k]);
}

// ---- Wl/Wr fp32 -> bf16 (row-major [out][in] kept) ---------------------
__global__ __launch_bounds__(256) void wlr_prep(const float* __restrict__ Wl,
                                                const float* __restrict__ Wr,
                                                ushort_t* __restrict__ wb) {
  int i = blockIdx.x * 256 + threadIdx.x;
  if (i >= HD * HD) return;
  wb[i] = f2b(Wl[i]);
  wb[HD * HD + i] = f2b(Wr[i]);
}

// ---- conv1d SAME K=9 via MFMA implicit GEMM ----------------------------
template<int CI, bool AFFINE>
__global__ __launch_bounds__(256) void conv_mfma(
    const float* __restrict__ xin, const ushort_t* __restrict__ wtb,
    const float* __restrict__ bias, const float* __restrict__ scale,
    const float* __restrict__ shift, float* __restrict__ outp)
{
  constexpr int LDSW = CI + 8;                    // row stride (bf16 elems)
  constexpr int L2CI = (CI == 64) ? 6 : 7;
  const int t0 = blockIdx.x * 64;
  const int b  = blockIdx.y;
  __shared__ __align__(16) ushort_t xs[72 * LDSW];

  const int tid = threadIdx.x;
  const float* xb = xin + (size_t)b * CI * NT;

  // ---- stage input tile: t in [t0-4, t0+68), all CI channels ----
  for (int u = tid; u < CI * 18; u += 256) {
    const int ci = u & (CI - 1);
    const int tq = u >> L2CI;
    const int gt = t0 - 4 + tq * 4;
    float4 v = make_float4(0.f, 0.f, 0.f, 0.f);
    const float* src = xb + (size_t)ci * NT + gt;
    if (gt >= 0 && gt + 3 < NT) {
      v = *reinterpret_cast<const float4*>(src);
    } else {
      float* vp = &v.x;
      #pragma unroll
      for (int e = 0; e < 4; ++e) {
        const int g = gt + e;
        if (g >= 0 && g < NT) vp[e] = src[e];
      }
    }
    float* vp = &v.x;
    #pragma unroll
    for (int e = 0; e < 4; ++e) {
      float val = vp[e];
      if (AFFINE) {
        const int g = gt + e;
        if (g >= 0 && g < NT) val = val * scale[g & 127] + shift[g & 127];
      }
      xs[(tq * 4 + e) * LDSW + ci] = f2b(val);
    }
  }
  __syncthreads();

  // ---- MFMA main loop ----
  const int lane = tid & 63;
  const int wid  = tid >> 6;
  const int wo   = wid >> 1;                      // o half (64)
  const int wt   = wid & 1;                       // t half (32)
  const int l15  = lane & 15;
  const int lk   = lane >> 4;                     // k-chunk 0..3

  f32x4 acc[4][2];
  #pragma unroll
  for (int mr = 0; mr < 4; ++mr)
    #pragma unroll
    for (int nr = 0; nr < 2; ++nr) acc[mr][nr] = (f32x4){0.f, 0.f, 0.f, 0.f};

  const ushort_t* wbase = wtb + (size_t)(wo * 64 + l15) * CI + lk * 8;

  for (int k = 0; k < NK; ++k) {
    const ushort_t* wk = wbase + (size_t)k * HD * CI;
    #pragma unroll
    for (int cc = 0; cc < CI / 32; ++cc) {
      short8 bfr[2];
      #pragma unroll
      for (int nr = 0; nr < 2; ++nr)
        bfr[nr] = *reinterpret_cast<const short8*>(
            &xs[(wt * 32 + nr * 16 + l15 + k) * LDSW + cc * 32 + lk * 8]);
      #pragma unroll
      for (int mr = 0; mr < 4; ++mr) {
        const short8 afr = *reinterpret_cast<const short8*>(wk + mr * 16 * CI + cc * 32);
        #pragma unroll
        for (int nr = 0; nr < 2; ++nr)
          acc[mr][nr] = __builtin_amdgcn_mfma_f32_16x16x32_bf16(afr, bfr[nr], acc[mr][nr], 0, 0, 0);
      }
    }
  }

  // ---- epilogue: bias + relu, coalesced dword stores along t ----
  const int tcol = t0 + wt * 32 + l15;            // + nr*16
  #pragma unroll
  for (int mr = 0; mr < 4; ++mr) {
    #pragma unroll
    for (int e = 0; e < 4; ++e) {
      const int o = wo * 64 + mr * 16 + lk * 4 + e;
      const float bv = bias[o];
      float* orow = outp + ((size_t)b * HD + o) * NT;
      #pragma unroll
      for (int nr = 0; nr < 2; ++nr) {
        float v = acc[mr][nr][e] + bv;
        orow[tcol + nr * 16] = v > 0.f ? v : 0.f;
      }
    }
  }
}

// ---- fused xl/xr GEMM via MFMA: xl = nf@Wl.T+bl, xr = nf@Wr.T+br -------
__global__ __launch_bounds__(256) void gemm_xlxr_mfma(
    const float* __restrict__ nf, const ushort_t* __restrict__ wb,
    const float* __restrict__ bl, const float* __restrict__ br,
    float* __restrict__ xl, float* __restrict__ xr)
{
  const int n0 = blockIdx.x * 64;
  __shared__ __align__(16) ushort_t nfs[64 * 136];   // 64 rows x (128+8) bf16
  const int tid = threadIdx.x;

  // stage 64x128 fp32 -> bf16 (coalesced 32B/thread)
  for (int u = tid; u < 64 * 16; u += 256) {
    const int r = u >> 4, c8 = (u & 15) * 8;
    const float* src = nf + (size_t)(n0 + r) * HD + c8;
    const float4 v0 = *reinterpret_cast<const float4*>(src);
    const float4 v1 = *reinterpret_cast<const float4*>(src + 4);
    ushort_t tmp[8] = {f2b(v0.x), f2b(v0.y), f2b(v0.z), f2b(v0.w),
                       f2b(v1.x), f2b(v1.y), f2b(v1.z), f2b(v1.w)};
    *reinterpret_cast<short8*>(&nfs[r * 136 + c8]) = *reinterpret_cast<const short8*>(tmp);
  }
  __syncthreads();

  const int lane = tid & 63;
  const int wid  = tid >> 6;                      // wave owns nodes wid*16..+16
  const int l15  = lane & 15;
  const int lk   = lane >> 4;

  f32x4 accl[8], accr[8];
  #pragma unroll
  for (int nt = 0; nt < 8; ++nt) {
    accl[nt] = (f32x4){0.f, 0.f, 0.f, 0.f};
    accr[nt] = (f32x4){0.f, 0.f, 0.f, 0.f};
  }

  #pragma unroll
  for (int kc = 0; kc < 4; ++kc) {
    const short8 afr = *reinterpret_cast<const short8*>(
        &nfs[(wid * 16 + l15) * 136 + kc * 32 + lk * 8]);
    const ushort_t* wrow = wb + (size_t)l15 * HD + kc * 32 + lk * 8;
    #pragma unroll
    for (int nt = 0; nt < 8; ++nt) {
      const short8 bfl = *reinterpret_cast<const short8*>(wrow + nt * 16 * HD);
      const short8 bfr = *reinterpret_cast<const short8*>(wrow + HD * HD + nt * 16 * HD);
      accl[nt] = __builtin_amdgcn_mfma_f32_16x16x32_bf16(afr, bfl, accl[nt], 0, 0, 0);
      accr[nt] = __builtin_amdgcn_mfma_f32_16x16x32_bf16(afr, bfr, accr[nt], 0, 0, 0);
    }
  }

  #pragma unroll
  for (int nt = 0; nt < 8; ++nt) {
    const int feat = nt * 16 + l15;
    const float bvl = bl[feat], bvr = br[feat];
    #pragma unroll
    for (int e = 0; e < 4; ++e) {
      const size_t row = (size_t)(n0 + wid * 16 + lk * 4 + e) * HD;
      xl[row + feat] = accl[nt][e] + bvl;
      xr[row + feat] = accr[nt][e] + bvr;
    }
  }
}

// ---- CSR construction by destination -----------------------------------
__global__ __launch_bounds__(256) void csr_count(const int* __restrict__ esrc,
                                                 const int* __restrict__ edst,
                                                 u32* __restrict__ cnt) {
  const int eid = blockIdx.x * 256 + threadIdx.x;
  if (eid >= NTOT) return;
  const int d = (eid < NE) ? edst[eid] : eid - NE;
  atomicAdd(&cnt[d], 1u);
}

// exclusive scan, stage 1: per-block (256) scan + block totals (grid = 1024)
__global__ __launch_bounds__(256) void scan1(const u32* __restrict__ cnt,
                                             u32* __restrict__ rs,
                                             u32* __restrict__ bsum) {
  __shared__ u32 tmp[256];
  const int t = threadIdx.x;
  const int i = blockIdx.x * 256 + t;
  const u32 v = cnt[i];
  tmp[t] = v;
  __syncthreads();
  for (int off = 1; off < 256; off <<= 1) {
    const u32 a = (t >= off) ? tmp[t - off] : 0u;
    __syncthreads();
    tmp[t] += a;
    __syncthreads();
  }
  rs[i] = tmp[t] - v;                            // exclusive
  if (t == 255) bsum[blockIdx.x] = tmp[255];
}

// stage 2: single block scans the 1024 block totals (exclusive, in place)
__global__ __launch_bounds__(1024) void scan2(u32* __restrict__ bsum) {
  __shared__ u32 tmp[1024];
  const int t = threadIdx.x;
  const u32 v = bsum[t];
  tmp[t] = v;
  __syncthreads();
  for (int off = 1; off < 1024; off <<= 1) {
    const u32 a = (t >= off) ? tmp[t - off] : 0u;
    __syncthreads();
    tmp[t] += a;
    __syncthreads();
  }
  bsum[t] = tmp[t] - v;
}

// stage 3: add block offsets; also init scatter cursors
__global__ __launch_bounds__(256) void scan3(u32* __restrict__ rs,
                                             const u32* __restrict__ bsum,
                                             u32* __restrict__ pos) {
  const int i = blockIdx.x * 256 + threadIdx.x;
  const u32 r = rs[i] + bsum[blockIdx.x];
  rs[i] = r;
  pos[i] = r;
}

__global__ __launch_bounds__(256) void csr_scatter(const int* __restrict__ esrc,
                                                   const int* __restrict__ edst,
                                                   u32* __restrict__ pos,
                                                   int* __restrict__ csr) {
  const int eid = blockIdx.x * 256 + threadIdx.x;
  if (eid >= NTOT) return;
  int s_, d_;
  if (eid < NE) { s_ = esrc[eid]; d_ = edst[eid]; } else { s_ = d_ = eid - NE; }
  const u32 p = atomicAdd(&pos[d_], 1u);
  csr[p] = s_;
}

// ---- fused GATv2: score + online softmax + aggregate + finalize + BN stats
// one wave per dst node (16 dsts/wave). Writes GAT output IN-PLACE over xr
// (each row is read only by its owner wave, before the write).
__global__ __launch_bounds__(256) void gat_fused(
    const int* __restrict__ csr, const u32* __restrict__ rs,
    const u32* __restrict__ cnt, const float* __restrict__ xl,
    float* __restrict__ xrout, const float* __restrict__ att,
    const float* __restrict__ gbias, float* __restrict__ stats)
{
  __shared__ float sacc[2][128];
  const int tid = threadIdx.x;
  if (tid < 128) { sacc[0][tid] = 0.f; sacc[1][tid] = 0.f; }
  __syncthreads();
  const int lane = tid & 63;
  const int wid  = tid >> 6;
  const float attl = att[lane], atth = att[lane + 64];
  const float gbl = gbias[lane], gbh = gbias[lane + 64];
  float s1l = 0.f, s2l = 0.f, s1h = 0.f, s2h = 0.f;
  const int dbase = blockIdx.x * 64 + wid * 16;

  for (int i = 0; i < 16; ++i) {
    const int d = dbase + i;
    float* xrow = xrout + (size_t)d * HD;
    const float xrl = xrow[lane], xrh = xrow[lane + 64];
    const u32 start = rs[d];
    const u32 deg = cnt[d];                      // >= 1 (self loop)
    float m = -INFINITY, s = 0.f, accl = 0.f, acch = 0.f;
    for (u32 j = 0; j < deg; ++j) {
      const int src = csr[start + j];
      const float* xls = xl + (size_t)src * HD;
      const float xll = xls[lane], xlh = xls[lane + 64];
      float q0 = xll + xrl; q0 = q0 > 0.f ? q0 : 0.2f * q0;
      float q1 = xlh + xrh; q1 = q1 > 0.f ? q1 : 0.2f * q1;
      float v = attl * q0 + atth * q1;
      #pragma unroll
      for (int off = 32; off > 0; off >>= 1) v += __shfl_xor(v, off);
      const float nm = fmaxf(m, v);
      const float sc = expf(m - nm);             // 0 on first edge (m=-inf)
      const float w  = expf(v - nm);
      s = s * sc + w;
      accl = accl * sc + w * xll;
      acch = acch * sc + w * xlh;
      m = nm;
    }
    const float inv = 1.f / (s + 1e-16f);
    float o0 = accl * inv + gbl; o0 = o0 > 0.f ? o0 : 0.f;
    float o1 = acch * inv + gbh; o1 = o1 > 0.f ? o1 : 0.f;
    xrow[lane] = o0;
    xrow[lane + 64] = o1;
    s1l += o0; s2l += o0 * o0;
    s1h += o1; s2h += o1 * o1;
  }

  atomicAdd(&sacc[0][lane], s1l); atomicAdd(&sacc[0][lane + 64], s1h);
  atomicAdd(&sacc[1][lane], s2l); atomicAdd(&sacc[1][lane + 64], s2h);
  __syncthreads();
  atomicAdd(stats + tid, sacc[tid >> 7][tid & 127]);  // [0..127]=sum, [128..255]=sumsq
}

// ---- BN scale/shift from stats -----------------------------------------
__global__ void bn_params(const float* __restrict__ stats, const float* __restrict__ gamma,
                          const float* __restrict__ beta, float* __restrict__ scsh)
{
  const int f = threadIdx.x;
  const float inv_n = 1.f / (float)NNODE;
  const float mu  = stats[f] * inv_n;
  const float var = stats[HD + f] * inv_n - mu * mu;
  const float sc  = gamma[f] * rsqrtf(var + 1e-5f);
  scsh[f] = sc;
  scsh[HD + f] = beta[f] - mu * sc;
}

// ---- launch -------------------------------------------------------------
extern "C" void kernel_launch(void* const* d_in, const int* in_sizes, int n_in,
                              void* d_out, int out_size, void* d_ws, size_t ws_size,
                              hipStream_t stream) {
  const float* x        = (const float*)d_in[0];
  const int*   edge_raw = (const int*)  d_in[1];
  const float* conv1_w  = (const float*)d_in[2];
  const float* conv1_b  = (const float*)d_in[3];
  const float* Wl       = (const float*)d_in[4];
  const float* bl       = (const float*)d_in[5];
  const float* Wr       = (const float*)d_in[6];
  const float* br       = (const float*)d_in[7];
  const float* att      = (const float*)d_in[8];
  const float* gat_bias = (const float*)d_in[9];
  const float* bn_gamma = (const float*)d_in[10];
  const float* bn_beta  = (const float*)d_in[11];
  const float* conv2_w  = (const float*)d_in[12];
  const float* conv2_b  = (const float*)d_in[13];
  float* out = (float*)d_out;
  char*  ws  = (char*)d_ws;

  // d_out doubles as the conv1-output / GEMM-input buffer (dead until conv2's
  // final write). Workspace layout (bytes):
  const size_t o_xl   = 0;                        // NELEM f32 (xl)
  const size_t o_xr   = o_xl  + NELEM * 4;        // NELEM f32 (xr -> GAT out in-place)
  const size_t o_csr  = o_xr  + NELEM * 4;        // NTOT i32
  const size_t o_cnt  = o_csr + (size_t)NTOT * 4; // NNODE u32
  const size_t o_rs   = o_cnt + (size_t)NNODE * 4;// NNODE u32
  const size_t o_pos  = o_rs  + (size_t)NNODE * 4;// NNODE u32
  const size_t o_bs   = o_pos + (size_t)NNODE * 4;// 1024 u32
  const size_t o_st   = o_bs  + 1024 * 4;         // 4*HD f32 (sum,sumsq,scale,shift)
  const size_t o_ed   = o_st  + 4 * HD * 4;       // 2*NE i32
  const size_t o_flag = o_ed  + (size_t)2 * NE * 4;
  const size_t o_w1   = (o_flag + 64) & ~(size_t)63;        // 9*128*64 bf16
  const size_t o_w2   = o_w1 + (size_t)NK * HD * NCIN * 2;  // 9*128*128 bf16
  const size_t o_wlr  = o_w2 + (size_t)NK * HD * HD * 2;    // 2*128*128 bf16

  float* h     = out;                             // conv1 out == n_feat flat view
  float* xl    = (float*)(ws + o_xl);
  float* xr    = (float*)(ws + o_xr);
  int*   csr   = (int*)  (ws + o_csr);
  u32*   cnt   = (u32*)  (ws + o_cnt);
  u32*   rs    = (u32*)  (ws + o_rs);
  u32*   pos   = (u32*)  (ws + o_pos);
  u32*   bsum  = (u32*)  (ws + o_bs);
  float* stats = (float*)(ws + o_st);
  int*   ei32  = (int*)  (ws + o_ed);
  int*   flag  = (int*)  (ws + o_flag);
  ushort_t* w1b  = (ushort_t*)(ws + o_w1);
  ushort_t* w2b  = (ushort_t*)(ws + o_w2);
  ushort_t* wlrb = (ushort_t*)(ws + o_wlr);

  hipMemsetAsync(cnt,   0, (size_t)NNODE * 4, stream);
  hipMemsetAsync(stats, 0, 2 * HD * 4, stream);

  detect_edges<<<1, 256, 0, stream>>>(edge_raw, flag);
  convert_edges<<<(2 * NE + 255) / 256, 256, 0, stream>>>(edge_raw, flag, ei32);

  conv_w_prep<<<(NK * HD * NCIN + 255) / 256, 256, 0, stream>>>(conv1_w, w1b, NCIN);
  conv_w_prep<<<(NK * HD * HD + 255) / 256, 256, 0, stream>>>(conv2_w, w2b, HD);
  wlr_prep<<<(HD * HD + 255) / 256, 256, 0, stream>>>(Wl, Wr, wlrb);

  // CSR build (overlaps with convs/gemm in issue order; same stream = serialized, cheap)
  csr_count<<<(NTOT + 255) / 256, 256, 0, stream>>>(ei32, ei32 + NE, cnt);
  scan1<<<NNODE / 256, 256, 0, stream>>>(cnt, rs, bsum);
  scan2<<<1, 1024, 0, stream>>>(bsum);
  scan3<<<NNODE / 256, 256, 0, stream>>>(rs, bsum, pos);
  csr_scatter<<<(NTOT + 255) / 256, 256, 0, stream>>>(ei32, ei32 + NE, pos, csr);

  // conv1 + relu -> h (=d_out)  (flat view == n_feat [NNODE, HD])
  conv_mfma<NCIN, false><<<dim3(NT / 64, NB), 256, 0, stream>>>(
      x, w1b, conv1_b, nullptr, nullptr, h);

  gemm_xlxr_mfma<<<NNODE / 64, 256, 0, stream>>>(h, wlrb, bl, br, xl, xr);

  // fused GATv2 (score+softmax+aggregate+finalize+stats); xr -> GAT out in-place
  gat_fused<<<NNODE / 64, 256, 0, stream>>>(csr, rs, cnt, xl, xr, att, gat_bias, stats);

  bn_params<<<1, HD, 0, stream>>>(stats, bn_gamma, bn_beta, stats + 2 * HD);

  // conv2 with fused BN affine on stage (note: BN feature index == t & 127)
  conv_mfma<HD, true><<<dim3(NT / 64, NB), 256, 0, stream>>>(
      xr, w2b, conv2_b, stats + 2 * HD, stats + 3 * HD, out);
}

// Round 7
// 976.277 us; speedup vs baseline: 3.5168x; 1.2001x over previous
//
#include <hip/hip_runtime.h>

// ---- problem constants -------------------------------------------------
#define NB    128                 // batch
#define NCIN  64                  // conv1 in channels
#define NT    2048                // time
#define HD    128                 // hidden / heads*feat
#define NK    9                   // kernel size
#define NE    600000              // edges
#define NNODE (NB*NT)             // 262144 nodes
#define NTOT  (NE + NNODE)        // edges + self loops = 862144
static const size_t NELEM = (size_t)NNODE * HD;   // 33554432

typedef unsigned int u32;
typedef unsigned short ushort_t;
typedef __attribute__((ext_vector_type(8))) short short8;
typedef __attribute__((ext_vector_type(4))) float f32x4;

// fp32 -> bf16 (RNE), bit-level
__device__ __forceinline__ ushort_t f2b(float f) {
  u32 x = __float_as_uint(f);
  return (ushort_t)((x + 0x7fffu + ((x >> 16) & 1u)) >> 16);
}

// ---- edge index layout detection (int64 vs int32) ----------------------
__global__ __launch_bounds__(256) void detect_edges(const int* __restrict__ ebuf,
                                                    int* __restrict__ flag) {
  __shared__ int s;
  if (threadIdx.x == 0) s = 0;
  __syncthreads();
  int any = 0;
  for (int i = threadIdx.x; i < 512; i += 256)
    if (ebuf[2 * i + 1] != 0) any = 1;           // int64 LE -> high words are 0
  if (any) atomicOr(&s, 1);
  __syncthreads();
  if (threadIdx.x == 0) *flag = s;               // s!=0 -> buffer is int32
}

__global__ __launch_bounds__(256) void convert_edges(const int* __restrict__ ebuf,
                                                     const int* __restrict__ flag,
                                                     int* __restrict__ out) {
  int i = blockIdx.x * 256 + threadIdx.x;
  if (i >= 2 * NE) return;
  out[i] = (*flag) ? ebuf[i] : ebuf[2 * i];      // int64: take low word
}

// ---- conv weight transpose: w[o][ci][k] fp32 -> wt[k][o][ci] bf16 ------
__global__ __launch_bounds__(256) void conv_w_prep(const float* __restrict__ w,
                                                   ushort_t* __restrict__ wt,
                                                   int CI) {
  int idx = blockIdx.x * 256 + threadIdx.x;
  if (idx >= NK * HD * CI) return;
  const int ci = idx % CI;
  const int o  = (idx / CI) % HD;
  const int k  = idx / (CI * HD);
  wt[idx] = f2b(w[(o * CI + ci) * NK + k]);
}

// ---- Wl/Wr fp32 -> bf16 (row-major [out][in] kept) ---------------------
__global__ __launch_bounds__(256) void wlr_prep(const float* __restrict__ Wl,
                                                const float* __restrict__ Wr,
                                                ushort_t* __restrict__ wb) {
  int i = blockIdx.x * 256 + threadIdx.x;
  if (i >= HD * HD) return;
  wb[i] = f2b(Wl[i]);
  wb[HD * HD + i] = f2b(Wr[i]);
}

// ---- conv1d SAME K=9 via MFMA implicit GEMM, t-tile 128 ----------------
// out[b][o][t] = relu(bias[o] + sum_{ci,k} w[o][ci][k] * aff(in[b][ci][t+k-4]))
// Block: 128 o x 128 t. 4 waves = 2(o) x 2(t); wave tile 64o x 64t,
// mr=4 x nr=4 MFMA frags. A (weights) prefetched one step ahead from L2.
template<int CI, bool AFFINE>
__global__ __launch_bounds__(256) void conv_mfma(
    const float* __restrict__ xin, const ushort_t* __restrict__ wtb,
    const float* __restrict__ bias, const float* __restrict__ scale,
    const float* __restrict__ shift, float* __restrict__ outp)
{
  constexpr int LDSW = CI + 8;                    // row stride (bf16 elems)
  constexpr int NCC  = CI / 32;                   // 32-chunk count along ci
  constexpr int NIDX = NK * NCC;
  const int t0 = blockIdx.x * 128;
  const int b  = blockIdx.y;
  __shared__ __align__(16) ushort_t xs[136 * LDSW];
  __shared__ float sc_s[128], sh_s[128];

  const int tid = threadIdx.x;
  const float* xb = xin + (size_t)b * CI * NT;

  if (AFFINE) {
    if (tid < 128) { sc_s[tid] = scale[tid]; sh_s[tid] = shift[tid]; }
    __syncthreads();
  }

  // ---- stage main region: t in [t0, t0+128), coalesced along t ----
  for (int u = tid; u < CI * 32; u += 256) {
    const int ci = u >> 5;
    const int qt = u & 31;
    const int gt = t0 + qt * 4;
    const float4 v = *reinterpret_cast<const float4*>(xb + (size_t)ci * NT + gt);
    const float* vp = &v.x;
    #pragma unroll
    for (int e = 0; e < 4; ++e) {
      float val = vp[e];
      if (AFFINE) { const int g = (gt + e) & 127; val = val * sc_s[g] + sh_s[g]; }
      xs[(qt * 4 + e + 4) * LDSW + ci] = f2b(val);
    }
  }
  // ---- halo: left quad [t0-4,t0), right quad [t0+128,t0+132) ----
  for (int u = tid; u < CI * 2; u += 256) {
    const int ci = u >> 1;
    const int side = u & 1;
    const int gt = side ? (t0 + 128) : (t0 - 4);
    const int rbase = side ? 132 : 0;
    const float* src = xb + (size_t)ci * NT + gt;
    #pragma unroll
    for (int e = 0; e < 4; ++e) {
      const int g = gt + e;
      float val = 0.f;
      if (g >= 0 && g < NT) {
        val = src[e];
        if (AFFINE) { const int gg = g & 127; val = val * sc_s[gg] + sh_s[gg]; }
      }
      xs[(rbase + e) * LDSW + ci] = f2b(val);
    }
  }
  __syncthreads();

  // ---- MFMA main loop with one-step-ahead A prefetch ----
  const int lane = tid & 63;
  const int wid  = tid >> 6;
  const int wo   = wid >> 1;                      // o half (64)
  const int wt   = wid & 1;                      // t half (64)
  const int l15  = lane & 15;
  const int lk   = lane >> 4;                     // k-chunk 0..3

  f32x4 acc[4][4];
  #pragma unroll
  for (int mr = 0; mr < 4; ++mr)
    #pragma unroll
    for (int nr = 0; nr < 4; ++nr) acc[mr][nr] = (f32x4){0.f, 0.f, 0.f, 0.f};

  const ushort_t* wbase = wtb + (size_t)(wo * 64 + l15) * CI + lk * 8;

  short8 a_cur[4], a_nxt[4];
  #pragma unroll
  for (int mr = 0; mr < 4; ++mr)
    a_cur[mr] = *reinterpret_cast<const short8*>(wbase + (size_t)mr * 16 * CI);

  for (int idx = 0; idx < NIDX; ++idx) {
    const int k  = idx / NCC;
    const int cc = idx % NCC;
    const int ni = idx + 1;
    if (ni < NIDX) {
      const int k2 = ni / NCC, c2 = ni % NCC;
      const ushort_t* wn = wbase + ((size_t)k2 * HD) * CI + c2 * 32;
      #pragma unroll
      for (int mr = 0; mr < 4; ++mr)
        a_nxt[mr] = *reinterpret_cast<const short8*>(wn + (size_t)mr * 16 * CI);
    }
    short8 bfr[4];
    #pragma unroll
    for (int nr = 0; nr < 4; ++nr)
      bfr[nr] = *reinterpret_cast<const short8*>(
          &xs[(wt * 64 + nr * 16 + l15 + k) * LDSW + cc * 32 + lk * 8]);
    #pragma unroll
    for (int mr = 0; mr < 4; ++mr)
      #pragma unroll
      for (int nr = 0; nr < 4; ++nr)
        acc[mr][nr] = __builtin_amdgcn_mfma_f32_16x16x32_bf16(a_cur[mr], bfr[nr], acc[mr][nr], 0, 0, 0);
    #pragma unroll
    for (int mr = 0; mr < 4; ++mr) a_cur[mr] = a_nxt[mr];
  }

  // ---- epilogue: bias + relu, coalesced dword stores along t ----
  const int tcol = t0 + wt * 64 + l15;            // + nr*16
  #pragma unroll
  for (int mr = 0; mr < 4; ++mr) {
    #pragma unroll
    for (int e = 0; e < 4; ++e) {
      const int o = wo * 64 + mr * 16 + lk * 4 + e;
      const float bv = bias[o];
      float* orow = outp + ((size_t)b * HD + o) * NT;
      #pragma unroll
      for (int nr = 0; nr < 4; ++nr) {
        float v = acc[mr][nr][e] + bv;
        orow[tcol + nr * 16] = v > 0.f ? v : 0.f;
      }
    }
  }
}

// ---- fused xl/xr GEMM via MFMA: xl = nf@Wl.T+bl, xr = nf@Wr.T+br -------
__global__ __launch_bounds__(256) void gemm_xlxr_mfma(
    const float* __restrict__ nf, const ushort_t* __restrict__ wb,
    const float* __restrict__ bl, const float* __restrict__ br,
    float* __restrict__ xl, float* __restrict__ xr)
{
  const int n0 = blockIdx.x * 64;
  __shared__ __align__(16) ushort_t nfs[64 * 136];   // 64 rows x (128+8) bf16
  const int tid = threadIdx.x;

  // stage 64x128 fp32 -> bf16 (coalesced 32B/thread)
  for (int u = tid; u < 64 * 16; u += 256) {
    const int r = u >> 4, c8 = (u & 15) * 8;
    const float* src = nf + (size_t)(n0 + r) * HD + c8;
    const float4 v0 = *reinterpret_cast<const float4*>(src);
    const float4 v1 = *reinterpret_cast<const float4*>(src + 4);
    ushort_t tmp[8] = {f2b(v0.x), f2b(v0.y), f2b(v0.z), f2b(v0.w),
                       f2b(v1.x), f2b(v1.y), f2b(v1.z), f2b(v1.w)};
    *reinterpret_cast<short8*>(&nfs[r * 136 + c8]) = *reinterpret_cast<const short8*>(tmp);
  }
  __syncthreads();

  const int lane = tid & 63;
  const int wid  = tid >> 6;                      // wave owns nodes wid*16..+16
  const int l15  = lane & 15;
  const int lk   = lane >> 4;

  f32x4 accl[8], accr[8];
  #pragma unroll
  for (int nt = 0; nt < 8; ++nt) {
    accl[nt] = (f32x4){0.f, 0.f, 0.f, 0.f};
    accr[nt] = (f32x4){0.f, 0.f, 0.f, 0.f};
  }

  #pragma unroll
  for (int kc = 0; kc < 4; ++kc) {
    const short8 afr = *reinterpret_cast<const short8*>(
        &nfs[(wid * 16 + l15) * 136 + kc * 32 + lk * 8]);
    const ushort_t* wrow = wb + (size_t)l15 * HD + kc * 32 + lk * 8;
    #pragma unroll
    for (int nt = 0; nt < 8; ++nt) {
      const short8 bfl = *reinterpret_cast<const short8*>(wrow + nt * 16 * HD);
      const short8 bfr = *reinterpret_cast<const short8*>(wrow + HD * HD + nt * 16 * HD);
      accl[nt] = __builtin_amdgcn_mfma_f32_16x16x32_bf16(afr, bfl, accl[nt], 0, 0, 0);
      accr[nt] = __builtin_amdgcn_mfma_f32_16x16x32_bf16(afr, bfr, accr[nt], 0, 0, 0);
    }
  }

  #pragma unroll
  for (int nt = 0; nt < 8; ++nt) {
    const int feat = nt * 16 + l15;
    const float bvl = bl[feat], bvr = br[feat];
    #pragma unroll
    for (int e = 0; e < 4; ++e) {
      const size_t row = (size_t)(n0 + wid * 16 + lk * 4 + e) * HD;
      xl[row + feat] = accl[nt][e] + bvl;
      xr[row + feat] = accr[nt][e] + bvr;
    }
  }
}

// ---- CSR construction by destination -----------------------------------
__global__ __launch_bounds__(256) void csr_count(const int* __restrict__ esrc,
                                                 const int* __restrict__ edst,
                                                 u32* __restrict__ cnt) {
  const int eid = blockIdx.x * 256 + threadIdx.x;
  if (eid >= NTOT) return;
  const int d = (eid < NE) ? edst[eid] : eid - NE;
  atomicAdd(&cnt[d], 1u);
}

// exclusive scan, stage 1: per-block (256) scan + block totals (grid = 1024)
__global__ __launch_bounds__(256) void scan1(const u32* __restrict__ cnt,
                                             u32* __restrict__ rs,
                                             u32* __restrict__ bsum) {
  __shared__ u32 tmp[256];
  const int t = threadIdx.x;
  const int i = blockIdx.x * 256 + t;
  const u32 v = cnt[i];
  tmp[t] = v;
  __syncthreads();
  for (int off = 1; off < 256; off <<= 1) {
    const u32 a = (t >= off) ? tmp[t - off] : 0u;
    __syncthreads();
    tmp[t] += a;
    __syncthreads();
  }
  rs[i] = tmp[t] - v;                            // exclusive
  if (t == 255) bsum[blockIdx.x] = tmp[255];
}

// stage 2: single block scans the 1024 block totals (exclusive, in place)
__global__ __launch_bounds__(1024) void scan2(u32* __restrict__ bsum) {
  __shared__ u32 tmp[1024];
  const int t = threadIdx.x;
  const u32 v = bsum[t];
  tmp[t] = v;
  __syncthreads();
  for (int off = 1; off < 1024; off <<= 1) {
    const u32 a = (t >= off) ? tmp[t - off] : 0u;
    __syncthreads();
    tmp[t] += a;
    __syncthreads();
  }
  bsum[t] = tmp[t] - v;
}

// stage 3: add block offsets; also init scatter cursors
__global__ __launch_bounds__(256) void scan3(u32* __restrict__ rs,
                                             const u32* __restrict__ bsum,
                                             u32* __restrict__ pos) {
  const int i = blockIdx.x * 256 + threadIdx.x;
  const u32 r = rs[i] + bsum[blockIdx.x];
  rs[i] = r;
  pos[i] = r;
}

__global__ __launch_bounds__(256) void csr_scatter(const int* __restrict__ esrc,
                                                   const int* __restrict__ edst,
                                                   u32* __restrict__ pos,
                                                   int* __restrict__ csr) {
  const int eid = blockIdx.x * 256 + threadIdx.x;
  if (eid >= NTOT) return;
  int s_, d_;
  if (eid < NE) { s_ = esrc[eid]; d_ = edst[eid]; } else { s_ = d_ = eid - NE; }
  const u32 p = atomicAdd(&pos[d_], 1u);
  csr[p] = s_;
}

// ---- fused GATv2: score + online softmax + aggregate + finalize + BN stats
// one wave per dst node (16 dsts/wave). Writes GAT output IN-PLACE over xr
// (each row is read only by its owner wave, before the write).
__global__ __launch_bounds__(256) void gat_fused(
    const int* __restrict__ csr, const u32* __restrict__ rs,
    const u32* __restrict__ cnt, const float* __restrict__ xl,
    float* __restrict__ xrout, const float* __restrict__ att,
    const float* __restrict__ gbias, float* __restrict__ stats)
{
  __shared__ float sacc[2][128];
  const int tid = threadIdx.x;
  if (tid < 128) { sacc[0][tid] = 0.f; sacc[1][tid] = 0.f; }
  __syncthreads();
  const int lane = tid & 63;
  const int wid  = tid >> 6;
  const float attl = att[lane], atth = att[lane + 64];
  const float gbl = gbias[lane], gbh = gbias[lane + 64];
  float s1l = 0.f, s2l = 0.f, s1h = 0.f, s2h = 0.f;
  const int dbase = blockIdx.x * 64 + wid * 16;

  for (int i = 0; i < 16; ++i) {
    const int d = dbase + i;
    float* xrow = xrout + (size_t)d * HD;
    const float xrl = xrow[lane], xrh = xrow[lane + 64];
    const u32 start = rs[d];
    const u32 deg = cnt[d];                      // >= 1 (self loop)
    float m = -INFINITY, s = 0.f, accl = 0.f, acch = 0.f;
    for (u32 j = 0; j < deg; ++j) {
      const int src = csr[start + j];
      const float* xls = xl + (size_t)src * HD;
      const float xll = xls[lane], xlh = xls[lane + 64];
      float q0 = xll + xrl; q0 = q0 > 0.f ? q0 : 0.2f * q0;
      float q1 = xlh + xrh; q1 = q1 > 0.f ? q1 : 0.2f * q1;
      float v = attl * q0 + atth * q1;
      #pragma unroll
      for (int off = 32; off > 0; off >>= 1) v += __shfl_xor(v, off);
      const float nm = fmaxf(m, v);
      const float sc = expf(m - nm);             // 0 on first edge (m=-inf)
      const float w  = expf(v - nm);
      s = s * sc + w;
      accl = accl * sc + w * xll;
      acch = acch * sc + w * xlh;
      m = nm;
    }
    const float inv = 1.f / (s + 1e-16f);
    float o0 = accl * inv + gbl; o0 = o0 > 0.f ? o0 : 0.f;
    float o1 = acch * inv + gbh; o1 = o1 > 0.f ? o1 : 0.f;
    xrow[lane] = o0;
    xrow[lane + 64] = o1;
    s1l += o0; s2l += o0 * o0;
    s1h += o1; s2h += o1 * o1;
  }

  atomicAdd(&sacc[0][lane], s1l); atomicAdd(&sacc[0][lane + 64], s1h);
  atomicAdd(&sacc[1][lane], s2l); atomicAdd(&sacc[1][lane + 64], s2h);
  __syncthreads();
  atomicAdd(stats + tid, sacc[tid >> 7][tid & 127]);  // [0..127]=sum, [128..255]=sumsq
}

// ---- BN scale/shift from stats -----------------------------------------
__global__ void bn_params(const float* __restrict__ stats, const float* __restrict__ gamma,
                          const float* __restrict__ beta, float* __restrict__ scsh)
{
  const int f = threadIdx.x;
  const float inv_n = 1.f / (float)NNODE;
  const float mu  = stats[f] * inv_n;
  const float var = stats[HD + f] * inv_n - mu * mu;
  const float sc  = gamma[f] * rsqrtf(var + 1e-5f);
  scsh[f] = sc;
  scsh[HD + f] = beta[f] - mu * sc;
}

// ---- launch -------------------------------------------------------------
extern "C" void kernel_launch(void* const* d_in, const int* in_sizes, int n_in,
                              void* d_out, int out_size, void* d_ws, size_t ws_size,
                              hipStream_t stream) {
  const float* x        = (const float*)d_in[0];
  const int*   edge_raw = (const int*)  d_in[1];
  const float* conv1_w  = (const float*)d_in[2];
  const float* conv1_b  = (const float*)d_in[3];
  const float* Wl       = (const float*)d_in[4];
  const float* bl       = (const float*)d_in[5];
  const float* Wr       = (const float*)d_in[6];
  const float* br       = (const float*)d_in[7];
  const float* att      = (const float*)d_in[8];
  const float* gat_bias = (const float*)d_in[9];
  const float* bn_gamma = (const float*)d_in[10];
  const float* bn_beta  = (const float*)d_in[11];
  const float* conv2_w  = (const float*)d_in[12];
  const float* conv2_b  = (const float*)d_in[13];
  float* out = (float*)d_out;
  char*  ws  = (char*)d_ws;

  // d_out doubles as the conv1-output / GEMM-input buffer (dead until conv2's
  // final write). Workspace layout (bytes):
  const size_t o_xl   = 0;                        // NELEM f32 (xl)
  const size_t o_xr   = o_xl  + NELEM * 4;        // NELEM f32 (xr -> GAT out in-place)
  const size_t o_csr  = o_xr  + NELEM * 4;        // NTOT i32
  const size_t o_cnt  = o_csr + (size_t)NTOT * 4; // NNODE u32
  const size_t o_rs   = o_cnt + (size_t)NNODE * 4;// NNODE u32
  const size_t o_pos  = o_rs  + (size_t)NNODE * 4;// NNODE u32
  const size_t o_bs   = o_pos + (size_t)NNODE * 4;// 1024 u32
  const size_t o_st   = o_bs  + 1024 * 4;         // 4*HD f32 (sum,sumsq,scale,shift)
  const size_t o_ed   = o_st  + 4 * HD * 4;       // 2*NE i32
  const size_t o_flag = o_ed  + (size_t)2 * NE * 4;
  const size_t o_w1   = (o_flag + 64) & ~(size_t)63;        // 9*128*64 bf16
  const size_t o_w2   = o_w1 + (size_t)NK * HD * NCIN * 2;  // 9*128*128 bf16
  const size_t o_wlr  = o_w2 + (size_t)NK * HD * HD * 2;    // 2*128*128 bf16

  float* h     = out;                             // conv1 out == n_feat flat view
  float* xl    = (float*)(ws + o_xl);
  float* xr    = (float*)(ws + o_xr);
  int*   csr   = (int*)  (ws + o_csr);
  u32*   cnt   = (u32*)  (ws + o_cnt);
  u32*   rs    = (u32*)  (ws + o_rs);
  u32*   pos   = (u32*)  (ws + o_pos);
  u32*   bsum  = (u32*)  (ws + o_bs);
  float* stats = (float*)(ws + o_st);
  int*   ei32  = (int*)  (ws + o_ed);
  int*   flag  = (int*)  (ws + o_flag);
  ushort_t* w1b  = (ushort_t*)(ws + o_w1);
  ushort_t* w2b  = (ushort_t*)(ws + o_w2);
  ushort_t* wlrb = (ushort_t*)(ws + o_wlr);

  hipMemsetAsync(cnt,   0, (size_t)NNODE * 4, stream);
  hipMemsetAsync(stats, 0, 2 * HD * 4, stream);

  detect_edges<<<1, 256, 0, stream>>>(edge_raw, flag);
  convert_edges<<<(2 * NE + 255) / 256, 256, 0, stream>>>(edge_raw, flag, ei32);

  conv_w_prep<<<(NK * HD * NCIN + 255) / 256, 256, 0, stream>>>(conv1_w, w1b, NCIN);
  conv_w_prep<<<(NK * HD * HD + 255) / 256, 256, 0, stream>>>(conv2_w, w2b, HD);
  wlr_prep<<<(HD * HD + 255) / 256, 256, 0, stream>>>(Wl, Wr, wlrb);

  // CSR build
  csr_count<<<(NTOT + 255) / 256, 256, 0, stream>>>(ei32, ei32 + NE, cnt);
  scan1<<<NNODE / 256, 256, 0, stream>>>(cnt, rs, bsum);
  scan2<<<1, 1024, 0, stream>>>(bsum);
  scan3<<<NNODE / 256, 256, 0, stream>>>(rs, bsum, pos);
  csr_scatter<<<(NTOT + 255) / 256, 256, 0, stream>>>(ei32, ei32 + NE, pos, csr);

  // conv1 + relu -> h (=d_out)  (flat view == n_feat [NNODE, HD])
  conv_mfma<NCIN, false><<<dim3(NT / 128, NB), 256, 0, stream>>>(
      x, w1b, conv1_b, nullptr, nullptr, h);

  gemm_xlxr_mfma<<<NNODE / 64, 256, 0, stream>>>(h, wlrb, bl, br, xl, xr);

  // fused GATv2 (score+softmax+aggregate+finalize+stats); xr -> GAT out in-place
  gat_fused<<<NNODE / 64, 256, 0, stream>>>(csr, rs, cnt, xl, xr, att, gat_bias, stats);

  bn_params<<<1, HD, 0, stream>>>(stats, bn_gamma, bn_beta, stats + 2 * HD);

  // conv2 with fused BN affine on stage (note: BN feature index == t & 127)
  conv_mfma<HD, true><<<dim3(NT / 128, NB), 256, 0, stream>>>(
      xr, w2b, conv2_b, stats + 2 * HD, stats + 3 * HD, out);
}